// Round 5
// baseline (503.171 us; speedup 1.0000x reference)
//
#include <hip/hip_runtime.h>
#include <stdint.h>

#define D_MODEL 2048
#define RANK    64
#define BATCH   16384

#define BM      32      // batch rows per block
#define LDA     72      // padded ushort row stride for nr LDS (144 B)

typedef unsigned short u16;
typedef __attribute__((ext_vector_type(8))) short  bf16x8;
typedef __attribute__((ext_vector_type(4))) float  f32x4;
typedef __attribute__((ext_vector_type(4))) unsigned short u16x4;

// ws layout (ushort elements):
#define WCAT_HI 0                         // [192][2048] bf16 hi of {W_dt;W_ph;W_B}
#define WCAT_LO (192*2048)
#define WC_HI   (2*192*2048)              // [2048][64] bf16 hi of W_C
#define WC_LO   (2*192*2048 + 2048*64)
// total 2 MiB in d_ws

__device__ __forceinline__ u16 f2bf(float f) {
    uint32_t u = __float_as_uint(f);
    u += 0x7fffu + ((u >> 16) & 1u);      // RNE
    return (u16)(u >> 16);
}
__device__ __forceinline__ float bf2f(u16 h) {
    return __uint_as_float(((uint32_t)h) << 16);
}

#define MFMA(a, b, c) __builtin_amdgcn_mfma_f32_16x16x32_bf16((a), (b), (c), 0, 0, 0)

// ---------------- prep: split weights into bf16 hi/lo ----------------
__global__ __launch_bounds__(256) void prep_split(
    const float* __restrict__ Wdt, const float* __restrict__ Wph,
    const float* __restrict__ WB,  const float* __restrict__ WC,
    u16* __restrict__ ws)
{
    int t = blockIdx.x * 256 + threadIdx.x;
    if (t < 98304) {                          // wcat: 192*2048/4
        int i = t << 2;
        int n = i >> 11, k = i & 2047;
        const float* src = (n < 64)  ? (Wdt + n * 2048 + k)
                         : (n < 128) ? (Wph + (n - 64) * 2048 + k)
                                     : (WB  + (n - 128) * 2048 + k);
        f32x4 v = *(const f32x4*)src;
        u16x4 hi, lo;
        #pragma unroll
        for (int j = 0; j < 4; ++j) {
            hi[j] = f2bf(v[j]);
            lo[j] = f2bf(v[j] - bf2f(hi[j]));
        }
        *(u16x4*)(ws + WCAT_HI + i) = hi;
        *(u16x4*)(ws + WCAT_LO + i) = lo;
    } else {                                  // W_C: 2048*64/4
        int i = (t - 98304) << 2;
        f32x4 v = *(const f32x4*)(WC + i);
        u16x4 hi, lo;
        #pragma unroll
        for (int j = 0; j < 4; ++j) {
            hi[j] = f2bf(v[j]);
            lo[j] = f2bf(v[j] - bf2f(hi[j]));
        }
        *(u16x4*)(ws + WC_HI + i) = hi;
        *(u16x4*)(ws + WC_LO + i) = lo;
    }
}

// ---------------- fused main kernel ----------------
// 512 threads = 8 waves: wm = w>>2 (batch half), wg = w&3 (rank / d-column split).
// Stage 1 (barrier-free): D = Wcat_frag · x^T_frag. Lane owns batch row
//   brow = r0 + wm*16 + l15 and, per g, ranks wg*16 + lg*4 + j (j=0..3).
//   x frags loaded straight from global (8 k-contiguous floats/lane, 128B
//   lines fully used), converted to bf16 hi/lo in regs. bf16x3: hh+lh+hl.
// Middle: fully vectorized f32x4 per lane (1 batch row x 4 consecutive ranks).
// Stage 2: D = W_C_frag · nre^T_frag; nre exchanged via 9KB LDS (one barrier);
//   output store is one f32x4 per lane per tile.
__global__ __launch_bounds__(512, 4) void mamba_fused(
    const float* __restrict__ x,
    const float* __restrict__ state_re, const float* __restrict__ state_im,
    const float* __restrict__ b_dt, const float* __restrict__ b_ph,
    const float* __restrict__ A_real, const float* __restrict__ A_imag,
    const u16* __restrict__ ws,
    float* __restrict__ dout)
{
    __shared__ __align__(16) u16 nr_hi[BM * LDA];
    __shared__ __align__(16) u16 nr_lo[BM * LDA];

    const u16* wcat_hi = ws + WCAT_HI;
    const u16* wcat_lo = ws + WCAT_LO;
    const u16* wc_hi   = ws + WC_HI;
    const u16* wc_lo   = ws + WC_LO;

    const int tid = threadIdx.x;
    const int w   = tid >> 6;
    const int wm  = w >> 2;            // batch half 0..1
    const int wg  = w & 3;             // rank/d split 0..3
    const int l15 = tid & 15;
    const int lg  = (tid & 63) >> 4;   // k-group 0..3
    const int r0  = blockIdx.x * BM;

    const int brow_l = wm * 16 + l15;          // block-local batch row
    const int brow   = r0 + brow_l;            // global batch row (this lane's B-col)
    const size_t xbase = (size_t)brow * D_MODEL;
    const int kofs = lg * 8;

    f32x4 acc[3];                               // g=0 dt, 1 phase, 2 B_val
    #pragma unroll
    for (int g = 0; g < 3; ++g) acc[g] = (f32x4){0.f, 0.f, 0.f, 0.f};

    #pragma unroll 2
    for (int it = 0; it < D_MODEL / 32; ++it) {
        const int kg = it * 32 + kofs;
        const f32x4 xv0 = *(const f32x4*)(x + xbase + kg);
        const f32x4 xv1 = *(const f32x4*)(x + xbase + kg + 4);
        bf16x8 xh, xl;
        #pragma unroll
        for (int j = 0; j < 4; ++j) {
            u16 h0 = f2bf(xv0[j]);
            u16 h1 = f2bf(xv1[j]);
            xh[j]     = (short)h0;
            xh[4 + j] = (short)h1;
            xl[j]     = (short)f2bf(xv0[j] - bf2f(h0));
            xl[4 + j] = (short)f2bf(xv1[j] - bf2f(h1));
        }
        #pragma unroll
        for (int g = 0; g < 3; ++g) {
            const int n = ((g << 2) + wg) * 16 + l15;   // row of wcat
            const bf16x8 wh = *(const bf16x8*)(wcat_hi + (size_t)n * 2048 + kg);
            const bf16x8 wl = *(const bf16x8*)(wcat_lo + (size_t)n * 2048 + kg);
            acc[g] = MFMA(wh, xh, acc[g]);   // hi*hi
            acc[g] = MFMA(wl, xh, acc[g]);   // lo*hi
            acc[g] = MFMA(wh, xl, acc[g]);   // hi*lo (ll dropped)
        }
    }

    // ---------------- middle: vectorized state update ----------------
    float* out_main = dout;
    float* out_nre  = dout + (size_t)BATCH * D_MODEL;
    float* out_nim  = out_nre + (size_t)BATCH * RANK;

    const int rb = wg * 16 + lg * 4;            // first of this lane's 4 ranks
    const f32x4 bdt4 = *(const f32x4*)(b_dt  + rb);
    const f32x4 bph4 = *(const f32x4*)(b_ph  + rb);
    const f32x4 Are4 = *(const f32x4*)(A_real + rb);
    const f32x4 Aim4 = *(const f32x4*)(A_imag + rb);
    const f32x4 sre4 = *(const f32x4*)(state_re + (size_t)brow * RANK + rb);
    const f32x4 sim4 = *(const f32x4*)(state_im + (size_t)brow * RANK + rb);

    f32x4 nre4, nim4;
    u16x4 nh4, nl4;
    #pragma unroll
    for (int j = 0; j < 4; ++j) {
        const float ydt = acc[0][j] + bdt4[j];
        const float dtv = fmaxf(ydt, 0.f) + log1pf(expf(-fabsf(ydt)));  // softplus
        const float ph  = tanhf(acc[1][j] + bph4[j]) * 3.14159274101257324f;
        const float decay = expf(-dtv * expf(Are4[j]));
        const float angle = fmaf(dtv, Aim4[j], ph);
        float sn, cs;
        sincosf(angle, &sn, &cs);
        nre4[j] = (sre4[j] * cs - sim4[j] * sn) * decay + acc[2][j];
        nim4[j] = (sre4[j] * sn + sim4[j] * cs) * decay;
        const u16 h = f2bf(nre4[j]);
        nh4[j] = h;
        nl4[j] = f2bf(nre4[j] - bf2f(h));
    }
    *(f32x4*)(out_nre + (size_t)brow * RANK + rb) = nre4;
    *(f32x4*)(out_nim + (size_t)brow * RANK + rb) = nim4;
    *(u16x4*)(nr_hi + brow_l * LDA + rb) = nh4;
    *(u16x4*)(nr_lo + brow_l * LDA + rb) = nl4;
    __syncthreads();

    // ---------------- stage 2: out = new_re @ W_C^T (operand-swapped) ----------------
    bf16x8 nh[2], nl[2];                        // nre B-frags, held across N loop
    #pragma unroll
    for (int kk = 0; kk < 2; ++kk) {
        const int off = brow_l * LDA + kk * 32 + lg * 8;
        nh[kk] = *(const bf16x8*)(nr_hi + off);
        nl[kk] = *(const bf16x8*)(nr_lo + off);
    }

    #pragma unroll 2
    for (int nt = 0; nt < 32; ++nt) {
        const int dt0  = (wg << 9) + (nt << 4);   // d-tile base (wave wg owns 512 cols)
        const int drow = dt0 + l15;               // W_C row for A-frag
        bf16x8 ch[2], cl[2];
        #pragma unroll
        for (int kk = 0; kk < 2; ++kk) {
            const int off = (drow << 6) + kk * 32 + lg * 8;
            ch[kk] = *(const bf16x8*)(wc_hi + off);
            cl[kk] = *(const bf16x8*)(wc_lo + off);
        }
        f32x4 o = (f32x4){0.f, 0.f, 0.f, 0.f};
        #pragma unroll
        for (int kk = 0; kk < 2; ++kk) {
            o = MFMA(ch[kk], nh[kk], o);
            o = MFMA(cl[kk], nh[kk], o);
            o = MFMA(ch[kk], nl[kk], o);
        }
        // D: col=l15 -> batch row brow; rows lg*4+j -> d = dt0+lg*4+j (contiguous)
        *(f32x4*)(out_main + (size_t)brow * D_MODEL + dt0 + lg * 4) = o;
    }
}

extern "C" void kernel_launch(void* const* d_in, const int* in_sizes, int n_in,
                              void* d_out, int out_size, void* d_ws, size_t ws_size,
                              hipStream_t stream)
{
    const float* x        = (const float*)d_in[0];
    const float* state_re = (const float*)d_in[1];
    const float* state_im = (const float*)d_in[2];
    const float* W_dt     = (const float*)d_in[3];
    const float* b_dt     = (const float*)d_in[4];
    const float* W_ph     = (const float*)d_in[5];
    const float* b_ph     = (const float*)d_in[6];
    const float* W_B      = (const float*)d_in[7];
    const float* W_C      = (const float*)d_in[8];
    const float* A_real   = (const float*)d_in[9];
    const float* A_imag   = (const float*)d_in[10];
    u16*   ws  = (u16*)d_ws;     // needs 2 MiB
    float* out = (float*)d_out;

    prep_split<<<512, 256, 0, stream>>>(W_dt, W_ph, W_B, W_C, ws);
    mamba_fused<<<BATCH / BM, 512, 0, stream>>>(x, state_re, state_im, b_dt, b_ph,
                                                A_real, A_imag, ws, out);
}

// Round 6
// 468.902 us; speedup vs baseline: 1.0731x; 1.0731x over previous
//
#include <hip/hip_runtime.h>
#include <stdint.h>

#define D_MODEL 2048
#define RANK    64
#define BATCH   16384

#define BM      32      // batch rows per block
#define KSTEP   64      // K per staged iteration
#define LDA     72      // padded u16 row stride (144 B)

typedef unsigned short u16;
typedef __attribute__((ext_vector_type(8))) short  bf16x8;
typedef __attribute__((ext_vector_type(4))) float  f32x4;
typedef __attribute__((ext_vector_type(4))) unsigned short u16x4;

// ws layout (u16 elements):
#define WCAT_HI 0                         // [192][2048] bf16 hi of {W_dt;W_ph;W_B}
#define WCAT_LO (192*2048)
#define WC_HI   (2*192*2048)              // [2048][64] bf16 hi of W_C
#define WC_LO   (2*192*2048 + 2048*64)
// total 2 MiB in d_ws

__device__ __forceinline__ u16 f2bf(float f) {
    uint32_t u = __float_as_uint(f);
    u += 0x7fffu + ((u >> 16) & 1u);      // RNE
    return (u16)(u >> 16);
}
__device__ __forceinline__ float bf2f(u16 h) {
    return __uint_as_float(((uint32_t)h) << 16);
}

#define MFMA(a, b, c) __builtin_amdgcn_mfma_f32_16x16x32_bf16((a), (b), (c), 0, 0, 0)

// ---------------- prep: split weights into bf16 hi/lo ----------------
__global__ __launch_bounds__(256) void prep_split(
    const float* __restrict__ Wdt, const float* __restrict__ Wph,
    const float* __restrict__ WB,  const float* __restrict__ WC,
    u16* __restrict__ ws)
{
    int t = blockIdx.x * 256 + threadIdx.x;
    if (t < 98304) {                          // wcat: 192*2048/4
        int i = t << 2;
        int n = i >> 11, k = i & 2047;
        const float* src = (n < 64)  ? (Wdt + n * 2048 + k)
                         : (n < 128) ? (Wph + (n - 64) * 2048 + k)
                                     : (WB  + (n - 128) * 2048 + k);
        f32x4 v = *(const f32x4*)src;
        u16x4 hi, lo;
        #pragma unroll
        for (int j = 0; j < 4; ++j) {
            hi[j] = f2bf(v[j]);
            lo[j] = f2bf(v[j] - bf2f(hi[j]));
        }
        *(u16x4*)(ws + WCAT_HI + i) = hi;
        *(u16x4*)(ws + WCAT_LO + i) = lo;
    } else {                                  // W_C: 2048*64/4
        int i = (t - 98304) << 2;
        f32x4 v = *(const f32x4*)(WC + i);
        u16x4 hi, lo;
        #pragma unroll
        for (int j = 0; j < 4; ++j) {
            hi[j] = f2bf(v[j]);
            lo[j] = f2bf(v[j] - bf2f(hi[j]));
        }
        *(u16x4*)(ws + WC_HI + i) = hi;
        *(u16x4*)(ws + WC_LO + i) = lo;
    }
}

// ---------------- fused main kernel ----------------
// 512 threads = 8 waves: wm = w>>2 (batch half of BM=32), wg = w&3 (N split).
// Stage 1: cooperative x staging (f32->bf16 hi/lo, once per block) into LDS,
//   T14 early-issue prefetch of next K-step into regs before compute.
//   Wave does D = Wcat_frag · x^T_frag for n-tiles {wg, wg+4, wg+8}: 18 MFMA/K-step.
// Middle: per lane 1 batch row x 4 consecutive ranks, fully f32x4-vectorized.
// Stage 2: identical to R5 (proven): one barrier, nre via LDS, W_C frags from L2.
__global__ __launch_bounds__(512, 4) void mamba_fused(
    const float* __restrict__ x,
    const float* __restrict__ state_re, const float* __restrict__ state_im,
    const float* __restrict__ b_dt, const float* __restrict__ b_ph,
    const float* __restrict__ A_real, const float* __restrict__ A_imag,
    const u16* __restrict__ ws,
    float* __restrict__ dout)
{
    __shared__ __align__(16) u16 xa_hi[BM * LDA];
    __shared__ __align__(16) u16 xa_lo[BM * LDA];
    __shared__ __align__(16) u16 nr_hi[BM * LDA];
    __shared__ __align__(16) u16 nr_lo[BM * LDA];

    const u16* wcat_hi = ws + WCAT_HI;
    const u16* wcat_lo = ws + WCAT_LO;
    const u16* wc_hi   = ws + WC_HI;
    const u16* wc_lo   = ws + WC_LO;

    const int tid = threadIdx.x;
    const int w   = tid >> 6;
    const int wm  = w >> 2;            // batch half 0..1
    const int wg  = w & 3;             // rank/d split 0..3
    const int l15 = tid & 15;
    const int lg  = (tid & 63) >> 4;   // k-group 0..3
    const int r0  = blockIdx.x * BM;

    const int brow_l = wm * 16 + l15;          // block-local batch row (lane's D col)
    const int brow   = r0 + brow_l;

    // staging map: thread t covers x[r0 + (t>>4)][k0 + (t&15)*4 .. +3]
    const int srow = tid >> 4;
    const int sk4  = (tid & 15) << 2;
    const float* xsrc = x + (size_t)(r0 + srow) * D_MODEL + sk4;

    // hoisted loads: state + per-rank constants (latency hidden under stage 1)
    const int rb = wg * 16 + lg * 4;           // first of this lane's 4 ranks
    const f32x4 sre4 = *(const f32x4*)(state_re + (size_t)brow * RANK + rb);
    const f32x4 sim4 = *(const f32x4*)(state_im + (size_t)brow * RANK + rb);
    const f32x4 bdt4 = *(const f32x4*)(b_dt   + rb);
    const f32x4 bph4 = *(const f32x4*)(b_ph   + rb);
    const f32x4 Are4 = *(const f32x4*)(A_real + rb);
    const f32x4 Aim4 = *(const f32x4*)(A_imag + rb);

    f32x4 acc[3];                               // g=0 dt, 1 phase, 2 B_val
    #pragma unroll
    for (int g = 0; g < 3; ++g) acc[g] = (f32x4){0.f, 0.f, 0.f, 0.f};

    f32x4 v = *(const f32x4*)xsrc;              // prologue: K-step 0
    for (int it = 0; it < D_MODEL / KSTEP; ++it) {
        f32x4 vn = v;
        if (it < D_MODEL / KSTEP - 1)
            vn = *(const f32x4*)(xsrc + (it + 1) * KSTEP);   // T14: issue early
        __syncthreads();                        // previous compute done (LDS free)
        {
            u16x4 hi, lo;
            #pragma unroll
            for (int j = 0; j < 4; ++j) {
                hi[j] = f2bf(v[j]);
                lo[j] = f2bf(v[j] - bf2f(hi[j]));
            }
            *(u16x4*)(xa_hi + srow * LDA + sk4) = hi;
            *(u16x4*)(xa_lo + srow * LDA + sk4) = lo;
        }
        __syncthreads();
        const int k0 = it * KSTEP;
        #pragma unroll
        for (int kk = 0; kk < 2; ++kk) {
            const int klocal = kk * 32 + lg * 8;
            const bf16x8 xhf = *(const bf16x8*)(xa_hi + brow_l * LDA + klocal);
            const bf16x8 xlf = *(const bf16x8*)(xa_lo + brow_l * LDA + klocal);
            const int kg = k0 + klocal;
            #pragma unroll
            for (int g = 0; g < 3; ++g) {
                const int n = ((g << 2) + wg) * 16 + l15;   // wcat row
                const bf16x8 wh = *(const bf16x8*)(wcat_hi + (size_t)n * 2048 + kg);
                const bf16x8 wl = *(const bf16x8*)(wcat_lo + (size_t)n * 2048 + kg);
                acc[g] = MFMA(wh, xhf, acc[g]);   // hi*hi
                acc[g] = MFMA(wl, xhf, acc[g]);   // lo*hi
                acc[g] = MFMA(wh, xlf, acc[g]);   // hi*lo (ll dropped)
            }
        }
        v = vn;
    }

    // ---------------- middle: vectorized state update ----------------
    float* out_main = dout;
    float* out_nre  = dout + (size_t)BATCH * D_MODEL;
    float* out_nim  = out_nre + (size_t)BATCH * RANK;

    f32x4 nre4, nim4;
    u16x4 nh4, nl4;
    #pragma unroll
    for (int j = 0; j < 4; ++j) {
        const float ydt = acc[0][j] + bdt4[j];
        const float dtv = fmaxf(ydt, 0.f) + log1pf(expf(-fabsf(ydt)));  // softplus
        const float ph  = tanhf(acc[1][j] + bph4[j]) * 3.14159274101257324f;
        const float decay = expf(-dtv * expf(Are4[j]));
        const float angle = fmaf(dtv, Aim4[j], ph);
        float sn, cs;
        sincosf(angle, &sn, &cs);
        nre4[j] = (sre4[j] * cs - sim4[j] * sn) * decay + acc[2][j];
        nim4[j] = (sre4[j] * sn + sim4[j] * cs) * decay;
        const u16 h = f2bf(nre4[j]);
        nh4[j] = h;
        nl4[j] = f2bf(nre4[j] - bf2f(h));
    }
    *(f32x4*)(out_nre + (size_t)brow * RANK + rb) = nre4;
    *(f32x4*)(out_nim + (size_t)brow * RANK + rb) = nim4;
    *(u16x4*)(nr_hi + brow_l * LDA + rb) = nh4;
    *(u16x4*)(nr_lo + brow_l * LDA + rb) = nl4;
    __syncthreads();

    // ---------------- stage 2: out = new_re @ W_C^T (operand-swapped) ----------------
    bf16x8 nh[2], nl[2];                        // nre B-frags, held across N loop
    #pragma unroll
    for (int kk = 0; kk < 2; ++kk) {
        const int off = brow_l * LDA + kk * 32 + lg * 8;
        nh[kk] = *(const bf16x8*)(nr_hi + off);
        nl[kk] = *(const bf16x8*)(nr_lo + off);
    }

    #pragma unroll 2
    for (int nt = 0; nt < 32; ++nt) {
        const int dt0  = (wg << 9) + (nt << 4);   // wave wg owns d-cols [wg*512, +512)
        const int drow = dt0 + l15;               // W_C row for A-frag
        bf16x8 ch[2], cl[2];
        #pragma unroll
        for (int kk = 0; kk < 2; ++kk) {
            const int off = (drow << 6) + kk * 32 + lg * 8;
            ch[kk] = *(const bf16x8*)(wc_hi + off);
            cl[kk] = *(const bf16x8*)(wc_lo + off);
        }
        f32x4 o = (f32x4){0.f, 0.f, 0.f, 0.f};
        #pragma unroll
        for (int kk = 0; kk < 2; ++kk) {
            o = MFMA(ch[kk], nh[kk], o);
            o = MFMA(cl[kk], nh[kk], o);
            o = MFMA(ch[kk], nl[kk], o);
        }
        // D: col=l15 -> batch row brow; rows lg*4+j -> d = dt0+lg*4+j (contiguous)
        *(f32x4*)(out_main + (size_t)brow * D_MODEL + dt0 + lg * 4) = o;
    }
}

extern "C" void kernel_launch(void* const* d_in, const int* in_sizes, int n_in,
                              void* d_out, int out_size, void* d_ws, size_t ws_size,
                              hipStream_t stream)
{
    const float* x        = (const float*)d_in[0];
    const float* state_re = (const float*)d_in[1];
    const float* state_im = (const float*)d_in[2];
    const float* W_dt     = (const float*)d_in[3];
    const float* b_dt     = (const float*)d_in[4];
    const float* W_ph     = (const float*)d_in[5];
    const float* b_ph     = (const float*)d_in[6];
    const float* W_B      = (const float*)d_in[7];
    const float* W_C      = (const float*)d_in[8];
    const float* A_real   = (const float*)d_in[9];
    const float* A_imag   = (const float*)d_in[10];
    u16*   ws  = (u16*)d_ws;     // needs 2 MiB
    float* out = (float*)d_out;

    prep_split<<<512, 256, 0, stream>>>(W_dt, W_ph, W_B, W_C, ws);
    mamba_fused<<<BATCH / BM, 512, 0, stream>>>(x, state_re, state_im, b_dt, b_ph,
                                                A_real, A_imag, ws, out);
}

// Round 11
// 361.542 us; speedup vs baseline: 1.3917x; 1.2969x over previous
//
#include <hip/hip_runtime.h>
#include <stdint.h>

#define D_MODEL 2048
#define RANK    64
#define BATCH   16384

#define BM      32      // batch rows per block
#define KSTEP   64      // K per staged iteration
#define LDA     72      // padded u16 row stride (144 B)

typedef unsigned short u16;
typedef __attribute__((ext_vector_type(8))) short  bf16x8;
typedef __attribute__((ext_vector_type(4))) float  f32x4;
typedef __attribute__((ext_vector_type(4))) unsigned short u16x4;
typedef __attribute__((ext_vector_type(8))) unsigned short u16x8;

// ws layout (u16 elements) — MFMA-fragment-packed weights:
// P1: [ntile 12][kwin 64][lane 64][8]  A-frags of {W_dt;W_ph;W_B} (lane l holds
//      row ntile*16+(l&15), k = kwin*32+(l>>4)*8 .. +8)
// P2: [dtile 128][kwin 2][lane 64][8]  A-frags of W_C
#define P1_HI 0
#define P1_LO 393216
#define P2_HI 786432
#define P2_LO 917504
// total 1048576 u16 = 2 MiB

__device__ __forceinline__ u16 f2bf(float f) {
    uint32_t u = __float_as_uint(f);
    u += 0x7fffu + ((u >> 16) & 1u);      // RNE
    return (u16)(u >> 16);
}
__device__ __forceinline__ float bf2f(u16 h) {
    return __uint_as_float(((uint32_t)h) << 16);
}

#define MFMA(a, b, c) __builtin_amdgcn_mfma_f32_16x16x32_bf16((a), (b), (c), 0, 0, 0)

// ---------------- prep: split + pack weights into fragment order ----------------
// 65536 threads; thread = one (tile,kwin,lane) frag slot of 8 elems.
// Reads are scattered (one-time, 2 MB); writes are perfectly contiguous.
__global__ __launch_bounds__(256) void prep_pack(
    const float* __restrict__ Wdt, const float* __restrict__ Wph,
    const float* __restrict__ WB,  const float* __restrict__ WC,
    u16* __restrict__ ws)
{
    const int t = blockIdx.x * 256 + threadIdx.x;
    const float* src;
    u16 *dhi, *dlo;
    if (t < 49152) {                          // P1: 12*64*64 frag slots
        const int lane = t & 63;
        const int row  = (t >> 12) * 16 + (lane & 15);
        const int k0   = ((t >> 6) & 63) * 32 + (lane >> 4) * 8;
        src = (row < 64)  ? Wdt + row * 2048 + k0
            : (row < 128) ? Wph + (row - 64) * 2048 + k0
                          : WB  + (row - 128) * 2048 + k0;
        dhi = ws + P1_HI + t * 8;
        dlo = ws + P1_LO + t * 8;
    } else {                                  // P2: 128*2*64 frag slots
        const int t2   = t - 49152;
        const int lane = t2 & 63;
        const int row  = (t2 >> 7) * 16 + (lane & 15);
        const int k0   = ((t2 >> 6) & 1) * 32 + (lane >> 4) * 8;
        src = WC + row * 64 + k0;
        dhi = ws + P2_HI + t2 * 8;
        dlo = ws + P2_LO + t2 * 8;
    }
    const f32x4 a = *(const f32x4*)src;
    const f32x4 b = *(const f32x4*)(src + 4);
    u16x8 hi, lo;
    #pragma unroll
    for (int j = 0; j < 4; ++j) {
        hi[j]     = f2bf(a[j]);
        lo[j]     = f2bf(a[j] - bf2f(hi[j]));
        hi[4 + j] = f2bf(b[j]);
        lo[4 + j] = f2bf(b[j] - bf2f(hi[4 + j]));
    }
    *(u16x8*)dhi = hi;
    *(u16x8*)dlo = lo;
}

// ---------------- fused main kernel ----------------
// 256 threads = 4 waves; wave wg owns n-tiles {wg, wg+4, wg+8} and BOTH M-frags
// (block's 12 n-tiles covered exactly once -> no duplicate weight reads).
// All weight loads coalesced via packed frags (lane*16B contiguous).
// Stage 1: coop x->LDS bf16 hi/lo, T14 reg-prefetch of next K-step.
// Middle: lane owns 2 batch rows x 4 consecutive ranks, f32x4-vectorized.
// Stage 2: W_C frags packed; nre via LDS; f32x4 stores.
__global__ __launch_bounds__(256, 2) void mamba_fused(
    const float* __restrict__ x,
    const float* __restrict__ state_re, const float* __restrict__ state_im,
    const float* __restrict__ b_dt, const float* __restrict__ b_ph,
    const float* __restrict__ A_real, const float* __restrict__ A_imag,
    const u16* __restrict__ ws,
    float* __restrict__ dout)
{
    __shared__ __align__(16) u16 xa_hi[BM * LDA];
    __shared__ __align__(16) u16 xa_lo[BM * LDA];
    __shared__ __align__(16) u16 nr_hi[BM * LDA];
    __shared__ __align__(16) u16 nr_lo[BM * LDA];

    const u16* p1_hi = ws + P1_HI;
    const u16* p1_lo = ws + P1_LO;
    const u16* p2_hi = ws + P2_HI;
    const u16* p2_lo = ws + P2_LO;

    const int tid  = threadIdx.x;
    const int wg   = tid >> 6;          // wave 0..3 (n-tile / d-col split)
    const int lane = tid & 63;
    const int l15  = tid & 15;
    const int lg   = (tid & 63) >> 4;
    const int r0   = blockIdx.x * BM;

    // staging map: thread covers x[r0 + tid>>3][(tid&7)*8 .. +8) per K-step
    const int srow = tid >> 3;
    const int skb  = (tid & 7) << 3;
    const float* xsrc = x + (size_t)(r0 + srow) * D_MODEL + skb;

    // hoisted per-lane constants & state (latency hidden under stage 1)
    const int rb = wg * 16 + lg * 4;    // lane's first rank (same for dt/ph/B)
    const int brow0 = r0 + l15;         // lane's batch rows (D cols), m=0/1
    const int brow1 = r0 + 16 + l15;
    const f32x4 sre0 = *(const f32x4*)(state_re + (size_t)brow0 * RANK + rb);
    const f32x4 sre1 = *(const f32x4*)(state_re + (size_t)brow1 * RANK + rb);
    const f32x4 sim0 = *(const f32x4*)(state_im + (size_t)brow0 * RANK + rb);
    const f32x4 sim1 = *(const f32x4*)(state_im + (size_t)brow1 * RANK + rb);
    const f32x4 bdt4 = *(const f32x4*)(b_dt   + rb);
    const f32x4 bph4 = *(const f32x4*)(b_ph   + rb);
    const f32x4 Are4 = *(const f32x4*)(A_real + rb);
    const f32x4 Aim4 = *(const f32x4*)(A_imag + rb);

    f32x4 acc[3][2];                    // [g][m]  g=0 dt, 1 phase, 2 B_val
    #pragma unroll
    for (int g = 0; g < 3; ++g)
        #pragma unroll
        for (int m = 0; m < 2; ++m)
            acc[g][m] = (f32x4){0.f, 0.f, 0.f, 0.f};

    f32x4 va = *(const f32x4*)xsrc;     // prologue: K-step 0
    f32x4 vb = *(const f32x4*)(xsrc + 4);

    for (int it = 0; it < D_MODEL / KSTEP; ++it) {
        f32x4 na = va, nb = vb;
        if (it < D_MODEL / KSTEP - 1) {           // T14: issue next step early
            na = *(const f32x4*)(xsrc + (it + 1) * KSTEP);
            nb = *(const f32x4*)(xsrc + (it + 1) * KSTEP + 4);
        }
        __syncthreads();                          // prev compute done, LDS free
        {
            u16x4 h0, l0, h1, l1;
            #pragma unroll
            for (int j = 0; j < 4; ++j) {
                h0[j] = f2bf(va[j]);  l0[j] = f2bf(va[j] - bf2f(h0[j]));
                h1[j] = f2bf(vb[j]);  l1[j] = f2bf(vb[j] - bf2f(h1[j]));
            }
            *(u16x4*)(xa_hi + srow * LDA + skb)     = h0;
            *(u16x4*)(xa_hi + srow * LDA + skb + 4) = h1;
            *(u16x4*)(xa_lo + srow * LDA + skb)     = l0;
            *(u16x4*)(xa_lo + srow * LDA + skb + 4) = l1;
        }
        __syncthreads();
        #pragma unroll
        for (int kk = 0; kk < 2; ++kk) {
            const int klocal = kk * 32 + lg * 8;
            const bf16x8 xh0 = *(const bf16x8*)(xa_hi + l15 * LDA + klocal);
            const bf16x8 xl0 = *(const bf16x8*)(xa_lo + l15 * LDA + klocal);
            const bf16x8 xh1 = *(const bf16x8*)(xa_hi + (16 + l15) * LDA + klocal);
            const bf16x8 xl1 = *(const bf16x8*)(xa_lo + (16 + l15) * LDA + klocal);
            const int kwin = it * 2 + kk;
            #pragma unroll
            for (int g = 0; g < 3; ++g) {
                const int ntile = (g << 2) + wg;
                const size_t poff = (((size_t)ntile * 64 + kwin) * 64 + lane) * 8;
                const bf16x8 wh = *(const bf16x8*)(p1_hi + poff);  // coalesced 1KB
                const bf16x8 wl = *(const bf16x8*)(p1_lo + poff);
                acc[g][0] = MFMA(wh, xh0, acc[g][0]);
                acc[g][0] = MFMA(wl, xh0, acc[g][0]);
                acc[g][0] = MFMA(wh, xl0, acc[g][0]);
                acc[g][1] = MFMA(wh, xh1, acc[g][1]);
                acc[g][1] = MFMA(wl, xh1, acc[g][1]);
                acc[g][1] = MFMA(wh, xl1, acc[g][1]);
            }
        }
        va = na; vb = nb;
    }

    // ---------------- middle: vectorized state update (2 rows x 4 ranks) ----------------
    float* out_main = dout;
    float* out_nre  = dout + (size_t)BATCH * D_MODEL;
    float* out_nim  = out_nre + (size_t)BATCH * RANK;

    #pragma unroll
    for (int m = 0; m < 2; ++m) {
        const int   brow = m ? brow1 : brow0;
        const f32x4 sre4 = m ? sre1 : sre0;
        const f32x4 sim4 = m ? sim1 : sim0;
        f32x4 nre4, nim4;
        u16x4 nh4, nl4;
        #pragma unroll
        for (int j = 0; j < 4; ++j) {
            const float ydt = acc[0][m][j] + bdt4[j];
            const float dtv = fmaxf(ydt, 0.f) + log1pf(expf(-fabsf(ydt)));  // softplus
            const float ph  = tanhf(acc[1][m][j] + bph4[j]) * 3.14159274101257324f;
            const float decay = expf(-dtv * expf(Are4[j]));
            const float angle = fmaf(dtv, Aim4[j], ph);
            float sn, cs;
            sincosf(angle, &sn, &cs);
            nre4[j] = (sre4[j] * cs - sim4[j] * sn) * decay + acc[2][m][j];
            nim4[j] = (sre4[j] * sn + sim4[j] * cs) * decay;
            const u16 h = f2bf(nre4[j]);
            nh4[j] = h;
            nl4[j] = f2bf(nre4[j] - bf2f(h));
        }
        *(f32x4*)(out_nre + (size_t)brow * RANK + rb) = nre4;
        *(f32x4*)(out_nim + (size_t)brow * RANK + rb) = nim4;
        *(u16x4*)(nr_hi + (m * 16 + l15) * LDA + rb) = nh4;
        *(u16x4*)(nr_lo + (m * 16 + l15) * LDA + rb) = nl4;
    }
    __syncthreads();

    // ---------------- stage 2: out = new_re @ W_C^T ----------------
    bf16x8 nh[2][2], nl[2][2];          // [m][kk] nre B-frags, held in regs
    #pragma unroll
    for (int m = 0; m < 2; ++m)
        #pragma unroll
        for (int kk = 0; kk < 2; ++kk) {
            const int off = (m * 16 + l15) * LDA + kk * 32 + lg * 8;
            nh[m][kk] = *(const bf16x8*)(nr_hi + off);
            nl[m][kk] = *(const bf16x8*)(nr_lo + off);
        }

    #pragma unroll 2
    for (int nt = 0; nt < 32; ++nt) {
        const int dtile = (wg << 5) + nt;        // wave wg owns d-cols [wg*512,+512)
        bf16x8 ch[2], cl[2];
        #pragma unroll
        for (int kk = 0; kk < 2; ++kk) {
            const size_t poff = (((size_t)dtile * 2 + kk) * 64 + lane) * 8;
            ch[kk] = *(const bf16x8*)(p2_hi + poff);   // coalesced 1KB
            cl[kk] = *(const bf16x8*)(p2_lo + poff);
        }
        #pragma unroll
        for (int m = 0; m < 2; ++m) {
            f32x4 o = (f32x4){0.f, 0.f, 0.f, 0.f};
            #pragma unroll
            for (int kk = 0; kk < 2; ++kk) {
                o = MFMA(ch[kk], nh[m][kk], o);
                o = MFMA(cl[kk], nh[m][kk], o);
                o = MFMA(ch[kk], nl[m][kk], o);
            }
            const int brow = m ? brow1 : brow0;
            // D: col=l15 -> batch row; rows lg*4+j -> d = dtile*16+lg*4+j (contig)
            *(f32x4*)(out_main + (size_t)brow * D_MODEL + dtile * 16 + lg * 4) = o;
        }
    }
}

extern "C" void kernel_launch(void* const* d_in, const int* in_sizes, int n_in,
                              void* d_out, int out_size, void* d_ws, size_t ws_size,
                              hipStream_t stream)
{
    const float* x        = (const float*)d_in[0];
    const float* state_re = (const float*)d_in[1];
    const float* state_im = (const float*)d_in[2];
    const float* W_dt     = (const float*)d_in[3];
    const float* b_dt     = (const float*)d_in[4];
    const float* W_ph     = (const float*)d_in[5];
    const float* b_ph     = (const float*)d_in[6];
    const float* W_B      = (const float*)d_in[7];
    const float* W_C      = (const float*)d_in[8];
    const float* A_real   = (const float*)d_in[9];
    const float* A_imag   = (const float*)d_in[10];
    u16*   ws  = (u16*)d_ws;     // needs 2 MiB
    float* out = (float*)d_out;

    prep_pack<<<256, 256, 0, stream>>>(W_dt, W_ph, W_B, W_C, ws);
    mamba_fused<<<BATCH / BM, 256, 0, stream>>>(x, state_re, state_im, b_dt, b_ph,
                                                A_real, A_imag, ws, out);
}

// Round 12
// 329.366 us; speedup vs baseline: 1.5277x; 1.0977x over previous
//
#include <hip/hip_runtime.h>
#include <stdint.h>

#define D_MODEL 2048
#define RANK    64
#define BATCH   16384

#define BM      32      // batch rows per block
#define CHUNK   256     // K staged per barrier-pair (8 chunks total)
#define LDAC    264     // padded u16 row stride for x chunk (528 B)
#define LDAN    72      // padded u16 row stride for nre LDS

typedef unsigned short u16;
typedef __attribute__((ext_vector_type(8))) short  bf16x8;
typedef __attribute__((ext_vector_type(4))) float  f32x4;
typedef __attribute__((ext_vector_type(4))) unsigned short u16x4;
typedef __attribute__((ext_vector_type(8))) unsigned short u16x8;

// ws layout (u16 elements) — MFMA-fragment-packed weights (unchanged from R11):
// P1: [ntile 12][kwin 64][lane 64][8]  A-frags of {W_dt;W_ph;W_B}
// P2: [dtile 128][kwin 2][lane 64][8]  A-frags of W_C
#define P1_HI 0
#define P1_LO 393216
#define P2_HI 786432
#define P2_LO 917504
// total 2 MiB

__device__ __forceinline__ u16 f2bf(float f) {
    uint32_t u = __float_as_uint(f);
    u += 0x7fffu + ((u >> 16) & 1u);      // RNE
    return (u16)(u >> 16);
}
__device__ __forceinline__ float bf2f(u16 h) {
    return __uint_as_float(((uint32_t)h) << 16);
}

#define MFMA(a, b, c) __builtin_amdgcn_mfma_f32_16x16x32_bf16((a), (b), (c), 0, 0, 0)

// ---------------- prep: split + pack weights into fragment order (unchanged) ----------------
__global__ __launch_bounds__(256) void prep_pack(
    const float* __restrict__ Wdt, const float* __restrict__ Wph,
    const float* __restrict__ WB,  const float* __restrict__ WC,
    u16* __restrict__ ws)
{
    const int t = blockIdx.x * 256 + threadIdx.x;
    const float* src;
    u16 *dhi, *dlo;
    if (t < 49152) {                          // P1: 12*64*64 frag slots
        const int lane = t & 63;
        const int row  = (t >> 12) * 16 + (lane & 15);
        const int k0   = ((t >> 6) & 63) * 32 + (lane >> 4) * 8;
        src = (row < 64)  ? Wdt + row * 2048 + k0
            : (row < 128) ? Wph + (row - 64) * 2048 + k0
                          : WB  + (row - 128) * 2048 + k0;
        dhi = ws + P1_HI + t * 8;
        dlo = ws + P1_LO + t * 8;
    } else {                                  // P2: 128*2*64 frag slots
        const int t2   = t - 49152;
        const int lane = t2 & 63;
        const int row  = (t2 >> 7) * 16 + (lane & 15);
        const int k0   = ((t2 >> 6) & 1) * 32 + (lane >> 4) * 8;
        src = WC + row * 64 + k0;
        dhi = ws + P2_HI + t2 * 8;
        dlo = ws + P2_LO + t2 * 8;
    }
    const f32x4 a = *(const f32x4*)src;
    const f32x4 b = *(const f32x4*)(src + 4);
    u16x8 hi, lo;
    #pragma unroll
    for (int j = 0; j < 4; ++j) {
        hi[j]     = f2bf(a[j]);
        lo[j]     = f2bf(a[j] - bf2f(hi[j]));
        hi[4 + j] = f2bf(b[j]);
        lo[4 + j] = f2bf(b[j] - bf2f(hi[4 + j]));
    }
    *(u16x8*)dhi = hi;
    *(u16x8*)dlo = lo;
}

// ---------------- fused main kernel v3 ----------------
// 512 threads = 8 waves: wm = w>>2 (batch half), wg = w&3 (n-tile / d-col split).
// Stage 1: x staged in 256-K chunks (8 barrier-pairs TOTAL, vs 32 in R11).
//   Chunk c+1's global loads issued right after barrier2 of chunk c -> ~8 kwins
//   of compute (72 MFMA + loads) hide the latency before the drain at the next
//   barrier. Weight frags coalesced from packed P1 (L2/L3-resident).
// Middle: lane owns (1 batch row) x (4 consecutive ranks), f32x4-vectorized.
// Stage 2: packed W_C frags, 1-deep prefetch; nre exchanged via LDS (1 barrier).
__global__ __launch_bounds__(512, 4) void mamba_v3(
    const float* __restrict__ x,
    const float* __restrict__ state_re, const float* __restrict__ state_im,
    const float* __restrict__ b_dt, const float* __restrict__ b_ph,
    const float* __restrict__ A_real, const float* __restrict__ A_imag,
    const u16* __restrict__ ws,
    float* __restrict__ dout)
{
    __shared__ __align__(16) u16 xa_hi[BM * LDAC];   // 16.5 KB
    __shared__ __align__(16) u16 xa_lo[BM * LDAC];   // 16.5 KB
    __shared__ __align__(16) u16 nr_hi[BM * LDAN];   // 4.5 KB
    __shared__ __align__(16) u16 nr_lo[BM * LDAN];   // 4.5 KB -> 42 KB total

    const u16* p1_hi = ws + P1_HI;
    const u16* p1_lo = ws + P1_LO;
    const u16* p2_hi = ws + P2_HI;
    const u16* p2_lo = ws + P2_LO;

    const int tid  = threadIdx.x;
    const int w    = tid >> 6;
    const int wm   = w >> 2;            // batch half 0..1
    const int wg   = w & 3;             // n-tile / d-col split 0..3
    const int lane = tid & 63;
    const int l15  = tid & 15;
    const int lg   = lane >> 4;         // k-group 0..3
    const int r0   = blockIdx.x * BM;

    // staging map: thread t covers x[r0 + (t>>4)][c*256 + (t&15)*16 .. +16)
    const int srow = tid >> 4;
    const int skc  = (tid & 15) << 4;
    const float* xsrc = x + (size_t)(r0 + srow) * D_MODEL + skc;

    const int brow_l = wm * 16 + l15;   // block-local batch row (lane's D col)
    const int brow   = r0 + brow_l;
    const int rb     = wg * 16 + lg * 4; // lane's first rank

    f32x4 acc[3];                        // g=0 dt, 1 phase, 2 B_val
    #pragma unroll
    for (int g = 0; g < 3; ++g) acc[g] = (f32x4){0.f, 0.f, 0.f, 0.f};

    // prologue: chunk 0 into regs
    f32x4 vx0 = *(const f32x4*)(xsrc);
    f32x4 vx1 = *(const f32x4*)(xsrc + 4);
    f32x4 vx2 = *(const f32x4*)(xsrc + 8);
    f32x4 vx3 = *(const f32x4*)(xsrc + 12);

    for (int c = 0; c < D_MODEL / CHUNK; ++c) {
        __syncthreads();                 // chunk c-1 readers done; LDS free
        {                                 // convert + write 16 floats -> LDS
            u16x4 h, l;
            #pragma unroll
            for (int j = 0; j < 4; ++j) { h[j]=f2bf(vx0[j]); l[j]=f2bf(vx0[j]-bf2f(h[j])); }
            *(u16x4*)(xa_hi + srow * LDAC + skc)      = h;
            *(u16x4*)(xa_lo + srow * LDAC + skc)      = l;
            #pragma unroll
            for (int j = 0; j < 4; ++j) { h[j]=f2bf(vx1[j]); l[j]=f2bf(vx1[j]-bf2f(h[j])); }
            *(u16x4*)(xa_hi + srow * LDAC + skc + 4)  = h;
            *(u16x4*)(xa_lo + srow * LDAC + skc + 4)  = l;
            #pragma unroll
            for (int j = 0; j < 4; ++j) { h[j]=f2bf(vx2[j]); l[j]=f2bf(vx2[j]-bf2f(h[j])); }
            *(u16x4*)(xa_hi + srow * LDAC + skc + 8)  = h;
            *(u16x4*)(xa_lo + srow * LDAC + skc + 8)  = l;
            #pragma unroll
            for (int j = 0; j < 4; ++j) { h[j]=f2bf(vx3[j]); l[j]=f2bf(vx3[j]-bf2f(h[j])); }
            *(u16x4*)(xa_hi + srow * LDAC + skc + 12) = h;
            *(u16x4*)(xa_lo + srow * LDAC + skc + 12) = l;
        }
        __syncthreads();
        if (c < D_MODEL / CHUNK - 1) {   // TRUE early issue: consumed next chunk,
            const float* nsrc = xsrc + (c + 1) * CHUNK;   // hidden under 8 kwins
            vx0 = *(const f32x4*)(nsrc);
            vx1 = *(const f32x4*)(nsrc + 4);
            vx2 = *(const f32x4*)(nsrc + 8);
            vx3 = *(const f32x4*)(nsrc + 12);
        }
        #pragma unroll 2
        for (int kw = 0; kw < CHUNK / 32; ++kw) {
            const int xoff = brow_l * LDAC + kw * 32 + lg * 8;
            const bf16x8 xh = *(const bf16x8*)(xa_hi + xoff);
            const bf16x8 xl = *(const bf16x8*)(xa_lo + xoff);
            const int kwin = c * (CHUNK / 32) + kw;
            #pragma unroll
            for (int g = 0; g < 3; ++g) {
                const size_t poff = (((size_t)((g << 2) + wg) * 64 + kwin) * 64 + lane) * 8;
                const bf16x8 wh = *(const bf16x8*)(p1_hi + poff);   // coalesced 1KB
                const bf16x8 wl = *(const bf16x8*)(p1_lo + poff);
                acc[g] = MFMA(wh, xh, acc[g]);   // hi*hi
                acc[g] = MFMA(wl, xh, acc[g]);   // lo*hi
                acc[g] = MFMA(wh, xl, acc[g]);   // hi*lo (ll dropped)
            }
        }
    }

    // ---------------- middle: vectorized state update ----------------
    float* out_main = dout;
    float* out_nre  = dout + (size_t)BATCH * D_MODEL;
    float* out_nim  = out_nre + (size_t)BATCH * RANK;

    const f32x4 sre4 = *(const f32x4*)(state_re + (size_t)brow * RANK + rb);
    const f32x4 sim4 = *(const f32x4*)(state_im + (size_t)brow * RANK + rb);
    const f32x4 bdt4 = *(const f32x4*)(b_dt   + rb);
    const f32x4 bph4 = *(const f32x4*)(b_ph   + rb);
    const f32x4 Are4 = *(const f32x4*)(A_real + rb);
    const f32x4 Aim4 = *(const f32x4*)(A_imag + rb);

    f32x4 nre4, nim4;
    u16x4 nh4, nl4;
    #pragma unroll
    for (int j = 0; j < 4; ++j) {
        const float ydt = acc[0][j] + bdt4[j];
        const float dtv = fmaxf(ydt, 0.f) + log1pf(expf(-fabsf(ydt)));  // softplus
        const float ph  = tanhf(acc[1][j] + bph4[j]) * 3.14159274101257324f;
        const float decay = expf(-dtv * expf(Are4[j]));
        const float angle = fmaf(dtv, Aim4[j], ph);
        float sn, cs;
        sincosf(angle, &sn, &cs);
        nre4[j] = (sre4[j] * cs - sim4[j] * sn) * decay + acc[2][j];
        nim4[j] = (sre4[j] * sn + sim4[j] * cs) * decay;
        const u16 h = f2bf(nre4[j]);
        nh4[j] = h;
        nl4[j] = f2bf(nre4[j] - bf2f(h));
    }
    *(f32x4*)(out_nre + (size_t)brow * RANK + rb) = nre4;
    *(f32x4*)(out_nim + (size_t)brow * RANK + rb) = nim4;
    *(u16x4*)(nr_hi + brow_l * LDAN + rb) = nh4;
    *(u16x4*)(nr_lo + brow_l * LDAN + rb) = nl4;
    __syncthreads();

    // ---------------- stage 2: out = new_re @ W_C^T (packed W_C, 1-deep prefetch) ----------------
    bf16x8 nh[2], nl[2];                 // nre B-frags for this lane's batch row
    #pragma unroll
    for (int kk = 0; kk < 2; ++kk) {
        const int off = brow_l * LDAN + kk * 32 + lg * 8;
        nh[kk] = *(const bf16x8*)(nr_hi + off);
        nl[kk] = *(const bf16x8*)(nr_lo + off);
    }

    bf16x8 ch[2], cl[2], chn[2], cln[2];
    {
        const int dtile0 = wg << 5;
        #pragma unroll
        for (int kk = 0; kk < 2; ++kk) {
            const size_t poff = (((size_t)dtile0 * 2 + kk) * 64 + lane) * 8;
            ch[kk] = *(const bf16x8*)(p2_hi + poff);
            cl[kk] = *(const bf16x8*)(p2_lo + poff);
        }
    }
    for (int nt = 0; nt < 32; ++nt) {
        if (nt < 31) {                   // prefetch next d-tile's frags
            const int dtn = (wg << 5) + nt + 1;
            #pragma unroll
            for (int kk = 0; kk < 2; ++kk) {
                const size_t poff = (((size_t)dtn * 2 + kk) * 64 + lane) * 8;
                chn[kk] = *(const bf16x8*)(p2_hi + poff);
                cln[kk] = *(const bf16x8*)(p2_lo + poff);
            }
        }
        f32x4 o = (f32x4){0.f, 0.f, 0.f, 0.f};
        #pragma unroll
        for (int kk = 0; kk < 2; ++kk) {
            o = MFMA(ch[kk], nh[kk], o);
            o = MFMA(cl[kk], nh[kk], o);
            o = MFMA(ch[kk], nl[kk], o);
        }
        const int dtile = (wg << 5) + nt;
        *(f32x4*)(out_main + (size_t)brow * D_MODEL + dtile * 16 + lg * 4) = o;
        #pragma unroll
        for (int kk = 0; kk < 2; ++kk) { ch[kk] = chn[kk]; cl[kk] = cln[kk]; }
    }
}

extern "C" void kernel_launch(void* const* d_in, const int* in_sizes, int n_in,
                              void* d_out, int out_size, void* d_ws, size_t ws_size,
                              hipStream_t stream)
{
    const float* x        = (const float*)d_in[0];
    const float* state_re = (const float*)d_in[1];
    const float* state_im = (const float*)d_in[2];
    const float* W_dt     = (const float*)d_in[3];
    const float* b_dt     = (const float*)d_in[4];
    const float* W_ph     = (const float*)d_in[5];
    const float* b_ph     = (const float*)d_in[6];
    const float* W_B      = (const float*)d_in[7];
    const float* W_C      = (const float*)d_in[8];
    const float* A_real   = (const float*)d_in[9];
    const float* A_imag   = (const float*)d_in[10];
    u16*   ws  = (u16*)d_ws;     // needs 2 MiB
    float* out = (float*)d_out;

    prep_pack<<<256, 256, 0, stream>>>(W_dt, W_ph, W_B, W_C, ws);
    mamba_v3<<<BATCH / BM, 512, 0, stream>>>(x, state_re, state_im, b_dt, b_ph,
                                             A_real, A_imag, ws, out);
}